// Round 1
// 174.854 us; speedup vs baseline: 1.0061x; 1.0061x over previous
//
#include <hip/hip_runtime.h>

// 3x3 median blur + residual, zero padding, x:(8,3,1024,1024) f32.
// Streaming rewrite: each block = 16 output rows x 1024 px strip, marched
// top-to-bottom with a P=6 register ring of input rows. Loads for row s+5
// are issued BEFORE computing output row s (3 rows always in flight ->
// counted vmcnt, never drain-to-zero). Halo columns via 2 extra strided
// dword loads (same cache lines as the dwordx4 -> L1 hits): no shfl, no
// LDS, no __syncthreads -> waves fully independent. Grid 64x24 = 1536
// blocks = 6 blocks/CU exactly; __launch_bounds__(256,6) keeps VGPR <= 85
// so the whole grid is resident (24 waves/CU vs 12.5 before).

typedef float v4f __attribute__((ext_vector_type(4)));

#define S2(a,b) { float _t=fminf(a,b); (b)=fmaxf(a,b); (a)=_t; }

__device__ __forceinline__ float med3f(float a, float b, float c) {
    return fmaxf(fminf(a, b), fminf(fmaxf(a, b), c));
}
__device__ __forceinline__ float max3f(float a, float b, float c) {
    return fmaxf(a, fmaxf(b, c));
}
__device__ __forceinline__ float min3f(float a, float b, float c) {
    return fminf(a, fminf(b, c));
}

constexpr int W  = 1024, H = 1024;
constexpr int RS = 16;     // output rows per block
constexpr int P  = 6;      // register ring depth (input rows in flight)

__global__ __launch_bounds__(256, 6) void median_blur_kernel(
    const float* __restrict__ xin, float* __restrict__ out)
{
    const int tx = threadIdx.x;
    const int x0 = tx << 2;                       // 4 px per thread, full row
    const int y0 = (int)blockIdx.x * RS;
    const size_t plane = (size_t)blockIdx.y * (size_t)(H * W);
    const float* base  = xin + plane;
    float*       obase = out + plane;

    const bool lE = (tx == 0);                    // image left edge thread
    const bool rE = (tx == 255);                  // image right edge thread
    const int  xl = lE ? x0       : x0 - 1;      // halo-left  addr (clamped; value zero-selected at use)
    const int  xr = rE ? x0 + 3   : x0 + 4;      // halo-right addr (clamped; value zero-selected at use)

    v4f   cc[P];                                  // center 4 px per ring row
    float ll[P], rr[P];                           // halo px per ring row

    const v4f vz = {0.0f, 0.0f, 0.0f, 0.0f};

    // ---- prologue: input rows s = 0..P-2   (input row y = y0-1+s)
#pragma unroll
    for (int s = 0; s < P - 1; ++s) {
        const int y = y0 - 1 + s;
        if (s == 0 && y < 0) {                    // top edge strip only (uniform)
            cc[s] = vz; ll[s] = 0.0f; rr[s] = 0.0f;
        } else {
            const float* rp = base + ((size_t)y << 10);
            cc[s] = *reinterpret_cast<const v4f*>(rp + x0);
            ll[s] = rp[xl];
            rr[s] = rp[xr];
        }
    }

    // ---- main march: output row i uses input rows s = i, i+1, i+2
#pragma unroll
    for (int i = 0; i < RS; ++i) {
        // prefetch input row s = i+P-1 into the slot freed last iteration;
        // consumed 3 iterations from now -> stays in flight under compute.
        if (i + P - 1 <= RS + 1) {                // compile-time bound (rows 0..RS+1 exist)
            const int s    = i + P - 1;
            const int slot = s % P;
            const int y    = y0 - 1 + s;
            if (s == RS + 1 && y >= H) {          // bottom edge strip only (uniform)
                cc[slot] = vz; ll[slot] = 0.0f; rr[slot] = 0.0f;
            } else {
                const float* rp = base + ((size_t)y << 10);
                cc[slot] = *reinterpret_cast<const v4f*>(rp + x0);
                ll[slot] = rp[xl];
                rr[slot] = rp[xr];
            }
            // pin the prefetch: do not let the scheduler sink these loads
            // below the compute (the load-sinking that serialized earlier
            // rounds). Nothing may cross this point.
            __builtin_amdgcn_sched_barrier(0);
        }

        const int sT = i % P, sM = (i + 1) % P, sB = (i + 2) % P;

        // 6-wide rows; image-edge halo columns are zero (pad semantics)
        const float t0 = lE ? 0.0f : ll[sT], t5 = rE ? 0.0f : rr[sT];
        const float m0 = lE ? 0.0f : ll[sM], m5 = rE ? 0.0f : rr[sM];
        const float b0 = lE ? 0.0f : ll[sB], b5 = rE ? 0.0f : rr[sB];
        const float t[6] = { t0, cc[sT].x, cc[sT].y, cc[sT].z, cc[sT].w, t5 };
        const float m[6] = { m0, cc[sM].x, cc[sM].y, cc[sM].z, cc[sM].w, m5 };
        const float b[6] = { b0, cc[sB].x, cc[sB].y, cc[sB].z, cc[sB].w, b5 };

        // vertical sort3 per column, then med3-of-candidates per output px
        float lo[6], mi[6], hi[6];
#pragma unroll
        for (int j = 0; j < 6; ++j) {
            float a = t[j], c0 = m[j], d = b[j];
            S2(a, c0); S2(c0, d); S2(a, c0);
            lo[j] = a; mi[j] = c0; hi[j] = d;
        }
        v4f o;
#pragma unroll
        for (int j = 0; j < 4; ++j) {
            const float mxlo = max3f(lo[j], lo[j + 1], lo[j + 2]);
            const float mnhi = min3f(hi[j], hi[j + 1], hi[j + 2]);
            const float mdmi = med3f(mi[j], mi[j + 1], mi[j + 2]);
            const float med  = med3f(mxlo, mdmi, mnhi);
            const float xc   = m[j + 1];
            o[j] = xc + 0.2f * (med - xc);
        }
        __builtin_nontemporal_store(o,
            reinterpret_cast<v4f*>(obase + ((size_t)(y0 + i) << 10) + x0));
    }
}

extern "C" void kernel_launch(void* const* d_in, const int* in_sizes, int n_in,
                              void* d_out, int out_size, void* d_ws, size_t ws_size,
                              hipStream_t stream) {
    const float* x = (const float*)d_in[0];
    float* out = (float*)d_out;
    const int planes = in_sizes[0] / (H * W);     // 24
    dim3 block(256);
    dim3 grid(H / RS, planes);                    // 64 x 24 = 1536 blocks = 6/CU
    median_blur_kernel<<<grid, block, 0, stream>>>(x, out);
}